// Round 2
// baseline (212.646 us; speedup 1.0000x reference)
//
#include <hip/hip_runtime.h>

#define NN 1024
#define NP (NN * NN)
#define TT 16
#define TDIM (NN / TT)
#define LST 99  // LDS floats per tile row (odd stride -> conflict-free transposed reads)

// LN + GEMV for one pair vector, 16 lanes cooperate. After return, ALL 16
// lanes hold the full acc[0..5] (pre-bias).
__device__ __forceinline__ void ln_gemv_16(
    const float* __restrict__ base, const float gam[8], const float bet[8],
    const float Wr[8][6], float acc[6])
{
  const int l = threadIdx.x & 15;
  const float4 xa = *(const float4*)(base + 4 * l);
  const float4 xb = *(const float4*)(base + 64 + 4 * l);
  float s = ((xa.x + xa.y) + (xa.z + xa.w)) + ((xb.x + xb.y) + (xb.z + xb.w));
  float sq = ((xa.x * xa.x + xa.y * xa.y) + (xa.z * xa.z + xa.w * xa.w)) +
             ((xb.x * xb.x + xb.y * xb.y) + (xb.z * xb.z + xb.w * xb.w));
#pragma unroll
  for (int m = 1; m <= 8; m <<= 1) {
    s += __shfl_xor(s, m);
    sq += __shfl_xor(sq, m);
  }
  const float mu = s * (1.f / 128.f);
  const float var = sq * (1.f / 128.f) - mu * mu;
  const float rstd = rsqrtf(var + 1e-5f);
  const float nmr = -mu * rstd;
  const float xv[8] = {xa.x, xa.y, xa.z, xa.w, xb.x, xb.y, xb.z, xb.w};
#pragma unroll
  for (int d = 0; d < 6; ++d) acc[d] = 0.f;
#pragma unroll
  for (int k = 0; k < 8; ++k) {
    const float h = fmaf(fmaf(xv[k], rstd, nmr), gam[k], bet[k]);
#pragma unroll
    for (int d = 0; d < 6; ++d) acc[d] = fmaf(h, Wr[k][d], acc[d]);
  }
#pragma unroll
  for (int d = 0; d < 6; ++d)
#pragma unroll
    for (int m = 1; m <= 8; m <<= 1) acc[d] += __shfl_xor(acc[d], m);
}

// Block (I,J), I<=J: LN+GEMV both tiles, symmetrize+mask in LDS, write xs to
// (I,J) and (J,I) coalesced, accumulate row exp-sums (row lse == col lse).
__global__ __launch_bounds__(256) void k_fused(
    const float* __restrict__ pairp, const int* __restrict__ seq,
    const float* __restrict__ gamma, const float* __restrict__ beta,
    const float* __restrict__ W, const float* __restrict__ bvec,
    float* __restrict__ xs, float* __restrict__ rowsum)
{
  const int I = blockIdx.y, J = blockIdx.x;
  if (J < I) return;
  const int tid = threadIdx.x;
  const int l = tid & 15;   // lane within pair-group
  const int g = tid >> 4;   // group id 0..15

  __shared__ float A[TT * LST];  // tile element (p,q,d) at A[p*LST + q*6 + d]

  float gam[8], bet[8], Wr[8][6];
#pragma unroll
  for (int k = 0; k < 2; ++k)
#pragma unroll
    for (int m = 0; m < 4; ++m) {
      const int c = 4 * l + 64 * k + m;
      const int idx = 4 * k + m;
      gam[idx] = gamma[c];
      bet[idx] = beta[c];
#pragma unroll
      for (int d = 0; d < 6; ++d) Wr[idx][d] = W[c * 6 + d];
    }
  const float bl = (l < 6) ? bvec[l] : 0.f;

  // ---- Phase A: x for tile (I,J); element (ti, tj=g) per pass ----
  const float* tileA = pairp + ((size_t)(I * TT) * NN + J * TT) * 128;
  for (int ti = 0; ti < TT; ++ti) {
    float acc[6];
    ln_gemv_16(tileA + ((size_t)ti * NN + g) * 128, gam, bet, Wr, acc);
    if (l < 6) A[ti * LST + g * 6 + l] = acc[l] + bl;
  }
  __syncthreads();

  if (I != J) {
    // ---- Phase B: x for tile (J,I); element (tib, g) -> xs[g][tib] in-place ----
    const float* tileB = pairp + ((size_t)(J * TT) * NN + I * TT) * 128;
    const int si = seq[I * TT + g];
    for (int tib = 0; tib < TT; ++tib) {
      float acc[6];
      ln_gemv_16(tileB + ((size_t)tib * NN + g) * 128, gam, bet, Wr, acc);
      if (l < 6) {
        const int dd = si - seq[J * TT + tib];
        const bool far = (dd > 3) || (dd < -3);
        const int idx = g * LST + tib * 6 + l;
        A[idx] = far ? 0.5f * (A[idx] + acc[l] + bl) : -1000000.0f;
      }
    }
    __syncthreads();

    // ---- Phase C: write xs tile (I,J), row sums for I-band ----
    {
      const int ti = tid >> 4, tj = tid & 15;
      const int i = I * TT + ti, j = J * TT + tj;
      float v[6], e[6];
#pragma unroll
      for (int d = 0; d < 6; ++d) {
        v[d] = A[ti * LST + tj * 6 + d];
        e[d] = __expf(v[d]);
      }
      float* op = xs + ((size_t)i * NN + j) * 6;
      *(float2*)(op) = make_float2(v[0], v[1]);
      *(float2*)(op + 2) = make_float2(v[2], v[3]);
      *(float2*)(op + 4) = make_float2(v[4], v[5]);
#pragma unroll
      for (int d = 0; d < 6; ++d)
#pragma unroll
        for (int m = 1; m <= 8; m <<= 1) e[d] += __shfl_xor(e[d], m);
      if (tj == 0) {
#pragma unroll
        for (int d = 0; d < 6; ++d) atomicAdd(&rowsum[i * 6 + d], e[d]);
      }
    }
    // ---- Phase D: write xs tile (J,I) transposed, row sums for J-band ----
    {
      const int r = tid >> 4, c = tid & 15;  // output (J*TT+r, I*TT+c) = A[c][r]
      float v[6], e[6];
#pragma unroll
      for (int d = 0; d < 6; ++d) {
        v[d] = A[c * LST + r * 6 + d];
        e[d] = __expf(v[d]);
      }
      const int jr = J * TT + r, ic = I * TT + c;
      float* op = xs + ((size_t)jr * NN + ic) * 6;
      *(float2*)(op) = make_float2(v[0], v[1]);
      *(float2*)(op + 2) = make_float2(v[2], v[3]);
      *(float2*)(op + 4) = make_float2(v[4], v[5]);
#pragma unroll
      for (int d = 0; d < 6; ++d)
#pragma unroll
        for (int m = 1; m <= 8; m <<= 1) e[d] += __shfl_xor(e[d], m);
      if (c == 0) {
#pragma unroll
        for (int d = 0; d < 6; ++d) atomicAdd(&rowsum[jr * 6 + d], e[d]);
      }
    }
  } else {
    // ---- Diagonal: xs = 0.5*(A + A^T), no LDS writeback needed ----
    const int ti = tid >> 4, tj = tid & 15;
    const int i = I * TT + ti, j = J * TT + tj;
    const int dd = seq[i] - seq[j];
    const bool far = (dd > 3) || (dd < -3);
    float v[6], e[6];
#pragma unroll
    for (int d = 0; d < 6; ++d) {
      const float a = A[ti * LST + tj * 6 + d];
      const float b = A[tj * LST + ti * 6 + d];
      v[d] = far ? 0.5f * (a + b) : -1000000.0f;
      e[d] = __expf(v[d]);
    }
    float* op = xs + ((size_t)i * NN + j) * 6;
    *(float2*)(op) = make_float2(v[0], v[1]);
    *(float2*)(op + 2) = make_float2(v[2], v[3]);
    *(float2*)(op + 4) = make_float2(v[4], v[5]);
#pragma unroll
    for (int d = 0; d < 6; ++d)
#pragma unroll
      for (int m = 1; m <= 8; m <<= 1) e[d] += __shfl_xor(e[d], m);
    if (tj == 0) {
#pragma unroll
      for (int d = 0; d < 6; ++d) atomicAdd(&rowsum[i * 6 + d], e[d]);
    }
  }
}

__global__ __launch_bounds__(256) void k_lse(
    const float* __restrict__ rowsum, float* __restrict__ lse)
{
  const int k = blockIdx.x * 256 + threadIdx.x;
  if (k < NN * 6) lse[k] = logf(1.0f + rowsum[k]);
}

// out = 4*xs - lse[i] - lse[j] - 2*log1p(sum_d exp(xs)) — pure stream
__global__ __launch_bounds__(256) void k_out(
    const float* __restrict__ xs, const float* __restrict__ lse,
    float* __restrict__ out)
{
  const int p = blockIdx.x * 256 + threadIdx.x;
  const int i = p >> 10;
  const int j = p & (NN - 1);

  const float* a = xs + (size_t)p * 6;
  const float2 a0 = *(const float2*)(a);
  const float2 a1 = *(const float2*)(a + 2);
  const float2 a2 = *(const float2*)(a + 4);
  const float v[6] = {a0.x, a0.y, a1.x, a1.y, a2.x, a2.y};

  float ssum = 0.f;
#pragma unroll
  for (int d = 0; d < 6; ++d) ssum += __expf(v[d]);
  const float lc2 = 2.f * logf(1.f + ssum);

  const float* li = lse + i * 6;
  const float* lj = lse + j * 6;
  float o[6];
#pragma unroll
  for (int d = 0; d < 6; ++d) o[d] = 4.f * v[d] - li[d] - lj[d] - lc2;

  float* op = out + (size_t)p * 6;
  *(float2*)(op) = make_float2(o[0], o[1]);
  *(float2*)(op + 2) = make_float2(o[2], o[3]);
  *(float2*)(op + 4) = make_float2(o[4], o[5]);
}

extern "C" void kernel_launch(void* const* d_in, const int* in_sizes, int n_in,
                              void* d_out, int out_size, void* d_ws, size_t ws_size,
                              hipStream_t stream) {
  const float* pairp = (const float*)d_in[0];
  const int* seq = (const int*)d_in[1];
  const float* gamma = (const float*)d_in[2];
  const float* beta = (const float*)d_in[3];
  const float* W = (const float*)d_in[4];
  const float* bvec = (const float*)d_in[5];
  float* out = (float*)d_out;

  float* xs = (float*)d_ws;                 // 1024*1024*6 fp32 = 24 MB
  float* rowsum = xs + (size_t)NP * 6;      // 1024*6
  float* lse = rowsum + NN * 6;             // 1024*6

  hipMemsetAsync(rowsum, 0, NN * 6 * sizeof(float), stream);
  k_fused<<<dim3(TDIM, TDIM), 256, 0, stream>>>(pairp, seq, gamma, beta, W,
                                                bvec, xs, rowsum);
  k_lse<<<(NN * 6 + 255) / 256, 256, 0, stream>>>(rowsum, lse);
  k_out<<<NP / 256, 256, 0, stream>>>(xs, lse, out);
}

// Round 3
// 175.375 us; speedup vs baseline: 1.2125x; 1.2125x over previous
//
#include <hip/hip_runtime.h>

#define NN 1024
#define NP (NN * NN)

// ---------------- k1: LayerNorm + GEMV (x = LN(pair) @ W + b) ----------------
// Unchanged from round 1 (proven linear-stream). 16 lanes per pair, 8 ch/lane.
__global__ __launch_bounds__(256) void k_ln_gemv(
    const float* __restrict__ pairp, const float* __restrict__ gamma,
    const float* __restrict__ beta, const float* __restrict__ W,
    const float* __restrict__ bvec, float* __restrict__ xout, int ngroups)
{
  const int l = threadIdx.x & 15;
  const int group = blockIdx.x * 16 + (threadIdx.x >> 4);

  float gam[8], bet[8], Wr[8][6];
#pragma unroll
  for (int k = 0; k < 2; ++k)
#pragma unroll
    for (int m = 0; m < 4; ++m) {
      const int c = 4 * l + 64 * k + m;
      const int idx = 4 * k + m;
      gam[idx] = gamma[c];
      bet[idx] = beta[c];
#pragma unroll
      for (int d = 0; d < 6; ++d) Wr[idx][d] = W[c * 6 + d];
    }
  const float bl = (l < 6) ? bvec[l] : 0.f;

  for (int p = group; p < NP; p += ngroups) {
    const float* base = pairp + (size_t)p * 128;
    const float4 xa = *(const float4*)(base + 4 * l);
    const float4 xb = *(const float4*)(base + 64 + 4 * l);

    float s = ((xa.x + xa.y) + (xa.z + xa.w)) + ((xb.x + xb.y) + (xb.z + xb.w));
    float sq = ((xa.x * xa.x + xa.y * xa.y) + (xa.z * xa.z + xa.w * xa.w)) +
               ((xb.x * xb.x + xb.y * xb.y) + (xb.z * xb.z + xb.w * xb.w));
#pragma unroll
    for (int m = 1; m <= 8; m <<= 1) {
      s += __shfl_xor(s, m);
      sq += __shfl_xor(sq, m);
    }
    const float mu = s * (1.f / 128.f);
    const float var = sq * (1.f / 128.f) - mu * mu;
    const float rstd = rsqrtf(var + 1e-5f);
    const float nmr = -mu * rstd;

    const float xv[8] = {xa.x, xa.y, xa.z, xa.w, xb.x, xb.y, xb.z, xb.w};
    float acc[6] = {0, 0, 0, 0, 0, 0};
#pragma unroll
    for (int k = 0; k < 8; ++k) {
      const float h = fmaf(fmaf(xv[k], rstd, nmr), gam[k], bet[k]);
#pragma unroll
      for (int d = 0; d < 6; ++d) acc[d] = fmaf(h, Wr[k][d], acc[d]);
    }
#pragma unroll
    for (int d = 0; d < 6; ++d)
#pragma unroll
      for (int m = 1; m <= 8; m <<= 1) acc[d] += __shfl_xor(acc[d], m);

    if (l < 6) {
      const float v = (l == 0) ? acc[0] : (l == 1) ? acc[1] : (l == 2) ? acc[2]
                     : (l == 3) ? acc[3] : (l == 4) ? acc[4] : acc[5];
      xout[(size_t)p * 6 + l] = v + bl;
    }
  }
}

// ---------------- k_sym: one-shot tiled symmetrize + mask + rowsum -----------
// Block (I,J): mirror tile (J,I) -> LDS (stride 193, conflict-free transposed
// read); xs[i,j] = mask ? -1e6 : 0.5*(x[i,j]+x[j,i]) written to OUT buffer
// coalesced; per-row exp-sums reduced in-wave, one atomic per row per block.
__global__ __launch_bounds__(256) void k_sym(
    const float* __restrict__ x, const int* __restrict__ seq,
    float* __restrict__ xs, float* __restrict__ rowsum)
{
  const int J = blockIdx.x, I = blockIdx.y;
  const int tid = threadIdx.x;
  __shared__ float M[32 * 193];

  // mirror tile: rows J*32+m, cols I*32..+31  (192 floats per row, 48 float4)
  const float* mb = x + ((size_t)(J * 32) * NN + I * 32) * 6;
  for (int k = tid; k < 1536; k += 256) {
    const int m = k / 48, f = k % 48;
    const float4 v = *(const float4*)(mb + (size_t)m * (NN * 6) + f * 4);
    float* dst = &M[m * 193 + f * 4];
    dst[0] = v.x; dst[1] = v.y; dst[2] = v.z; dst[3] = v.w;
  }
  __syncthreads();

  float es[4][6];
#pragma unroll
  for (int q = 0; q < 4; ++q) {
    const int e = tid + 256 * q;
    const int r = e >> 5, c = e & 31;
    const int i = I * 32 + r, j = J * 32 + c;
    const int dd = seq[i] - seq[j];
    const bool far = (dd > 3) || (dd < -3);
    const float* own = x + ((size_t)i * NN + j) * 6;
    const float2 o0 = *(const float2*)(own);
    const float2 o1 = *(const float2*)(own + 2);
    const float2 o2 = *(const float2*)(own + 4);
    const float* mr = &M[c * 193 + r * 6];  // x[j,i]
    float v[6];
    v[0] = far ? 0.5f * (o0.x + mr[0]) : -1000000.f;
    v[1] = far ? 0.5f * (o0.y + mr[1]) : -1000000.f;
    v[2] = far ? 0.5f * (o1.x + mr[2]) : -1000000.f;
    v[3] = far ? 0.5f * (o1.y + mr[3]) : -1000000.f;
    v[4] = far ? 0.5f * (o2.x + mr[4]) : -1000000.f;
    v[5] = far ? 0.5f * (o2.y + mr[5]) : -1000000.f;
    float* op = xs + ((size_t)i * NN + j) * 6;
    *(float2*)(op) = make_float2(v[0], v[1]);
    *(float2*)(op + 2) = make_float2(v[2], v[3]);
    *(float2*)(op + 4) = make_float2(v[4], v[5]);
#pragma unroll
    for (int d = 0; d < 6; ++d) es[q][d] = __expf(v[d]);
  }

  // reduce over c: lanes sharing (tid>>5) are one 32-lane half-wave
#pragma unroll
  for (int q = 0; q < 4; ++q)
#pragma unroll
    for (int d = 0; d < 6; ++d)
#pragma unroll
      for (int m = 1; m <= 16; m <<= 1) es[q][d] += __shfl_xor(es[q][d], m);

  if ((tid & 31) == 0) {
    const int w = tid >> 5;
#pragma unroll
    for (int q = 0; q < 4; ++q) {
      const int i = I * 32 + w + 8 * q;
#pragma unroll
      for (int d = 0; d < 6; ++d) atomicAdd(&rowsum[i * 6 + d], es[q][d]);
    }
  }
}

__global__ __launch_bounds__(256) void k_lse(
    const float* __restrict__ rowsum, float* __restrict__ lse)
{
  const int k = blockIdx.x * 256 + threadIdx.x;
  if (k < NN * 6) lse[k] = logf(1.0f + rowsum[k]);
}

// ------- k_out: in-place pure stream: out = 4*xs - lse_i - lse_j - 2*chnlse --
__global__ __launch_bounds__(256) void k_out(
    float* __restrict__ out, const float* __restrict__ lse)
{
  const int p = blockIdx.x * 256 + threadIdx.x;
  const int i = p >> 10;
  const int j = p & (NN - 1);

  float* a = out + (size_t)p * 6;
  const float2 a0 = *(const float2*)(a);
  const float2 a1 = *(const float2*)(a + 2);
  const float2 a2 = *(const float2*)(a + 4);
  const float v[6] = {a0.x, a0.y, a1.x, a1.y, a2.x, a2.y};

  float ssum = 0.f;
#pragma unroll
  for (int d = 0; d < 6; ++d) ssum += __expf(v[d]);
  const float lc2 = 2.f * logf(1.f + ssum);

  const float* li = lse + i * 6;
  const float* lj = lse + j * 6;
  float o[6];
#pragma unroll
  for (int d = 0; d < 6; ++d) o[d] = 4.f * v[d] - li[d] - lj[d] - lc2;

  *(float2*)(a) = make_float2(o[0], o[1]);
  *(float2*)(a + 2) = make_float2(o[2], o[3]);
  *(float2*)(a + 4) = make_float2(o[4], o[5]);
}

extern "C" void kernel_launch(void* const* d_in, const int* in_sizes, int n_in,
                              void* d_out, int out_size, void* d_ws, size_t ws_size,
                              hipStream_t stream) {
  const float* pairp = (const float*)d_in[0];
  const int* seq = (const int*)d_in[1];
  const float* gamma = (const float*)d_in[2];
  const float* beta = (const float*)d_in[3];
  const float* W = (const float*)d_in[4];
  const float* bvec = (const float*)d_in[5];
  float* out = (float*)d_out;

  float* x = (float*)d_ws;              // raw x: 1024*1024*6 fp32 = 24 MB
  float* rowsum = x + (size_t)NP * 6;   // 1024*6
  float* lse = rowsum + NN * 6;         // 1024*6

  hipMemsetAsync(rowsum, 0, NN * 6 * sizeof(float), stream);
  k_ln_gemv<<<2048, 256, 0, stream>>>(pairp, gamma, beta, W, bvec, x, 2048 * 16);
  k_sym<<<dim3(32, 32), 256, 0, stream>>>(x, seq, out, rowsum);  // xs -> out
  k_lse<<<(NN * 6 + 255) / 256, 256, 0, stream>>>(rowsum, lse);
  k_out<<<NP / 256, 256, 0, stream>>>(out, lse);
}